// Round 1
// baseline (395.511 us; speedup 1.0000x reference)
//
#include <hip/hip_runtime.h>
#include <math.h>

#define B_SZ 16384
#define D_DIM 128
#define A_SZ 8192
#define K_SZ 64
#define L2_REG_F 0.25f

__device__ __forceinline__ float wave_reduce_sum(float v) {
    #pragma unroll
    for (int off = 32; off > 0; off >>= 1)
        v += __shfl_xor(v, off, 64);
    return v;
}

__device__ __forceinline__ float wave_reduce_max(float v) {
    #pragma unroll
    for (int off = 32; off > 0; off >>= 1)
        v = fmaxf(v, __shfl_xor(v, off, 64));
    return v;
}

// mean L2 norm accumulator: one wave per row of image_embed
__global__ __launch_bounds__(256) void l2_kernel(const float* __restrict__ embed,
                                                 float* __restrict__ acc) {
    const int wave = threadIdx.x >> 6;
    const int lane = threadIdx.x & 63;
    const int row  = blockIdx.x * 4 + wave;
    const float2* r = (const float2*)(embed + (size_t)row * D_DIM);
    float2 v = r[lane];                       // 64 lanes x 2 floats = 128
    float ss = v.x * v.x + v.y * v.y;
    ss = wave_reduce_sum(ss);
    if (lane == 0) atomicAdd(acc, sqrtf(ss));
}

// n-pair loss: one wave per anchor, lane k handles negative k (K=64)
__global__ __launch_bounds__(256) void npair_kernel(const float* __restrict__ embed,
                                                    const int* __restrict__ anc_ind,
                                                    const int* __restrict__ pos_ind,
                                                    const int* __restrict__ neg_ind,
                                                    float* __restrict__ acc) {
    __shared__ __align__(16) float a_lds[4][D_DIM];
    const int wave = threadIdx.x >> 6;
    const int lane = threadIdx.x & 63;
    const int i    = blockIdx.x * 4 + wave;   // anchor index

    const int ai = anc_ind[i];
    const int pi = pos_ind[i];
    const float2* ar = (const float2*)(embed + (size_t)ai * D_DIM);
    const float2* pr = (const float2*)(embed + (size_t)pi * D_DIM);
    float2 a2 = ar[lane];
    float2 p2 = pr[lane];
    a_lds[wave][2 * lane]     = a2.x;
    a_lds[wave][2 * lane + 1] = a2.y;
    float ap = wave_reduce_sum(a2.x * p2.x + a2.y * p2.y);  // a . p (broadcast to all lanes)
    __syncthreads();

    // lane k: dot(a, n_k) with float4 loads over its gathered row
    const int ni = neg_ind[(size_t)i * K_SZ + lane];
    const float4* nr = (const float4*)(embed + (size_t)ni * D_DIM);
    const float4* al = (const float4*)a_lds[wave];
    float s = 0.f;
    #pragma unroll
    for (int j = 0; j < D_DIM / 4; ++j) {
        float4 n4 = nr[j];
        float4 a4 = al[j];                    // same addr across wave -> LDS broadcast, free
        s += a4.x * n4.x + a4.y * n4.y + a4.z * n4.z + a4.w * n4.w;
    }
    float inner = s - ap;

    // wave-wide stable logsumexp over K=64 lanes
    float m  = wave_reduce_max(inner);
    float se = wave_reduce_sum(expf(inner - m));
    if (lane == 0) {
        float lse = m + logf(se);
        // logaddexp(0, lse) = log(1 + exp(lse)), stable both directions
        float per = (lse > 0.f) ? lse + log1pf(expf(-lse)) : log1pf(expf(lse));
        atomicAdd(acc, per);
    }
}

__global__ void finalize_kernel(const float* __restrict__ acc, float* __restrict__ out) {
    // acc[0] = sum of norms over B rows, acc[1] = sum of per-anchor losses over A
    out[0] = acc[1] / (float)A_SZ + L2_REG_F * acc[0] / (float)B_SZ;
}

extern "C" void kernel_launch(void* const* d_in, const int* in_sizes, int n_in,
                              void* d_out, int out_size, void* d_ws, size_t ws_size,
                              hipStream_t stream) {
    const float* embed = (const float*)d_in[0];
    const int*   anc   = (const int*)d_in[1];
    const int*   pos   = (const int*)d_in[2];
    const int*   neg   = (const int*)d_in[3];
    float* out = (float*)d_out;
    float* acc = (float*)d_ws;    // acc[0]=l2 sum, acc[1]=npair sum

    hipMemsetAsync(acc, 0, 2 * sizeof(float), stream);
    l2_kernel<<<B_SZ / 4, 256, 0, stream>>>(embed, acc);
    npair_kernel<<<A_SZ / 4, 256, 0, stream>>>(embed, anc, pos, neg, acc + 1);
    finalize_kernel<<<1, 1, 0, stream>>>(acc, out);
}

// Round 2
// 115.842 us; speedup vs baseline: 3.4142x; 3.4142x over previous
//
#include <hip/hip_runtime.h>
#include <math.h>

#define B_SZ 16384
#define D_DIM 128
#define A_SZ 8192
#define K_SZ 64
#define L2_REG_F 0.25f
#define NBLK 256   // 256 blocks x 4 waves = 1024 waves

__device__ __forceinline__ float wave_reduce_sum(float v) {
    #pragma unroll
    for (int off = 32; off > 0; off >>= 1)
        v += __shfl_xor(v, off, 64);
    return v;
}

__device__ __forceinline__ float wave_reduce_max(float v) {
    #pragma unroll
    for (int off = 32; off > 0; off >>= 1)
        v = fmaxf(v, __shfl_xor(v, off, 64));
    return v;
}

// Fused: l2-norm sum over B rows + n-pair loss sum over A anchors.
// 1024 waves; each wave: 16 l2 rows + 8 anchors. One partial per block, no atomics.
__global__ __launch_bounds__(256) void main_kernel(const float* __restrict__ embed,
                                                   const int* __restrict__ anc_ind,
                                                   const int* __restrict__ pos_ind,
                                                   const int* __restrict__ neg_ind,
                                                   float* __restrict__ partial) {
    __shared__ __align__(16) float a_lds[4][D_DIM];
    __shared__ float red[4];
    const int wave = threadIdx.x >> 6;
    const int lane = threadIdx.x & 63;
    const int gw   = blockIdx.x * 4 + wave;   // global wave id, 0..1023

    // ---- phase 1: sum of L2 norms over rows of image_embed ----
    float acc_l2 = 0.f;
    #pragma unroll
    for (int it = 0; it < B_SZ / 1024; ++it) {
        const int row = gw + 1024 * it;
        const float2* r = (const float2*)(embed + (size_t)row * D_DIM);
        float2 v = r[lane];                   // 64 lanes x 2 floats = 128
        float ss = wave_reduce_sum(v.x * v.x + v.y * v.y);
        acc_l2 += sqrtf(ss);                  // same value on all lanes; use lane0's later
    }

    // ---- phase 2: n-pair loss, one anchor per wave-iteration, lane k = negative k ----
    float acc_np = 0.f;
    #pragma unroll
    for (int it = 0; it < A_SZ / 1024; ++it) {
        const int i  = gw + 1024 * it;        // anchor index
        const int ai = anc_ind[i];
        const int pi = pos_ind[i];
        const float2* ar = (const float2*)(embed + (size_t)ai * D_DIM);
        const float2* pr = (const float2*)(embed + (size_t)pi * D_DIM);
        float2 a2 = ar[lane];
        float2 p2 = pr[lane];
        a_lds[wave][2 * lane]     = a2.x;
        a_lds[wave][2 * lane + 1] = a2.y;
        float ap = wave_reduce_sum(a2.x * p2.x + a2.y * p2.y);  // a.p broadcast
        __syncthreads();                      // all waves run same trip count

        const int ni = neg_ind[(size_t)i * K_SZ + lane];
        const float4* nr = (const float4*)(embed + (size_t)ni * D_DIM);
        const float4* al = (const float4*)a_lds[wave];
        float s = 0.f;
        #pragma unroll
        for (int j = 0; j < D_DIM / 4; ++j) {
            float4 n4 = nr[j];
            float4 a4 = al[j];                // same addr across wave -> LDS broadcast
            s += a4.x * n4.x + a4.y * n4.y + a4.z * n4.z + a4.w * n4.w;
        }
        float inner = s - ap;

        float m  = wave_reduce_max(inner);
        float se = wave_reduce_sum(expf(inner - m));
        float lse = m + logf(se);
        float per = (lse > 0.f) ? lse + log1pf(expf(-lse)) : log1pf(expf(lse));
        acc_np += per;                        // same on all lanes; lane0's used
    }

    // ---- block reduction: pre-scale and emit one partial ----
    float combined = acc_np * (1.0f / (float)A_SZ)
                   + acc_l2 * (L2_REG_F / (float)B_SZ);
    if (lane == 0) red[wave] = combined;
    __syncthreads();
    if (threadIdx.x == 0)
        partial[blockIdx.x] = red[0] + red[1] + red[2] + red[3];
}

__global__ __launch_bounds__(256) void finalize_kernel(const float* __restrict__ partial,
                                                       float* __restrict__ out) {
    __shared__ float red[4];
    const int wave = threadIdx.x >> 6;
    const int lane = threadIdx.x & 63;
    float v = partial[threadIdx.x];           // 256 partials
    v = wave_reduce_sum(v);
    if (lane == 0) red[wave] = v;
    __syncthreads();
    if (threadIdx.x == 0)
        out[0] = red[0] + red[1] + red[2] + red[3];
}

extern "C" void kernel_launch(void* const* d_in, const int* in_sizes, int n_in,
                              void* d_out, int out_size, void* d_ws, size_t ws_size,
                              hipStream_t stream) {
    const float* embed = (const float*)d_in[0];
    const int*   anc   = (const int*)d_in[1];
    const int*   pos   = (const int*)d_in[2];
    const int*   neg   = (const int*)d_in[3];
    float* out     = (float*)d_out;
    float* partial = (float*)d_ws;            // NBLK floats, fully overwritten

    main_kernel<<<NBLK, 256, 0, stream>>>(embed, anc, pos, neg, partial);
    finalize_kernel<<<1, 256, 0, stream>>>(partial, out);
}

// Round 3
// 112.487 us; speedup vs baseline: 3.5161x; 1.0298x over previous
//
#include <hip/hip_runtime.h>
#include <math.h>

#define B_SZ 16384
#define D_DIM 128
#define A_SZ 8192
#define K_SZ 64
#define L2_REG_F 0.25f
#define NBLK 2048   // 2048 blocks x 4 waves = 8192 waves = 1 wave per anchor

__device__ __forceinline__ float wave_reduce_sum(float v) {
    #pragma unroll
    for (int off = 32; off > 0; off >>= 1)
        v += __shfl_xor(v, off, 64);
    return v;
}

__device__ __forceinline__ float wave_reduce_max(float v) {
    #pragma unroll
    for (int off = 32; off > 0; off >>= 1)
        v = fmaxf(v, __shfl_xor(v, off, 64));
    return v;
}

// Fused: l2-norm sum over B rows + n-pair loss over A anchors.
// 8192 waves; each wave: 2 l2 rows + 1 anchor. No atomics, no __syncthreads
// in the hot path (each wave touches only its own LDS slice).
__global__ __launch_bounds__(256) void main_kernel(const float* __restrict__ embed,
                                                   const int* __restrict__ anc_ind,
                                                   const int* __restrict__ pos_ind,
                                                   const int* __restrict__ neg_ind,
                                                   float* __restrict__ partial) {
    __shared__ __align__(16) float a_lds[4][D_DIM];
    __shared__ float red[4];
    const int wave = threadIdx.x >> 6;
    const int lane = threadIdx.x & 63;
    const int gw   = blockIdx.x * 4 + wave;   // global wave id == anchor id, 0..8191

    // ---- phase 1: sum of L2 norms, 2 consecutive rows per wave ----
    float acc_l2 = 0.f;
    #pragma unroll
    for (int r = 0; r < 2; ++r) {
        const int row = gw * 2 + r;
        const float2* rr = (const float2*)(embed + (size_t)row * D_DIM);
        float2 v = rr[lane];
        acc_l2 += sqrtf(wave_reduce_sum(v.x * v.x + v.y * v.y));
    }

    // ---- phase 2: this wave's anchor; lane k = negative k ----
    const int i  = gw;
    const int ai = anc_ind[i];
    const int pi = pos_ind[i];
    const int ni = neg_ind[(size_t)i * K_SZ + lane];   // coalesced 256B

    const float2* ar = (const float2*)(embed + (size_t)ai * D_DIM);
    const float2* pr = (const float2*)(embed + (size_t)pi * D_DIM);
    float2 a2 = ar[lane];
    float2 p2 = pr[lane];
    a_lds[wave][2 * lane]     = a2.x;
    a_lds[wave][2 * lane + 1] = a2.y;
    float ap = wave_reduce_sum(a2.x * p2.x + a2.y * p2.y);  // a.p, broadcast

    // dot(a, n_k): float4 loads, 4-way ILP accumulators; LDS reads are
    // same-address broadcast across the wave (conflict-free).
    const float4* nr = (const float4*)(embed + (size_t)ni * D_DIM);
    const float4* al = (const float4*)a_lds[wave];
    float s0 = 0.f, s1 = 0.f, s2 = 0.f, s3 = 0.f;
    #pragma unroll
    for (int j = 0; j < D_DIM / 4; j += 4) {
        float4 n0 = nr[j + 0], n1 = nr[j + 1], n2 = nr[j + 2], n3 = nr[j + 3];
        float4 a0 = al[j + 0], a1 = al[j + 1], a2v = al[j + 2], a3 = al[j + 3];
        s0 += a0.x * n0.x + a0.y * n0.y + a0.z * n0.z + a0.w * n0.w;
        s1 += a1.x * n1.x + a1.y * n1.y + a1.z * n1.z + a1.w * n1.w;
        s2 += a2v.x * n2.x + a2v.y * n2.y + a2v.z * n2.z + a2v.w * n2.w;
        s3 += a3.x * n3.x + a3.y * n3.y + a3.z * n3.z + a3.w * n3.w;
    }
    float inner = (s0 + s1) + (s2 + s3) - ap;

    // wave-wide stable logsumexp over K=64 lanes
    float m  = wave_reduce_max(inner);
    float se = wave_reduce_sum(__expf(inner - m));
    float lse = m + __logf(se);
    float per = (lse > 0.f) ? lse + log1pf(__expf(-lse)) : log1pf(__expf(lse));

    // ---- block reduction: pre-scale, one partial per block ----
    float combined = per * (1.0f / (float)A_SZ)
                   + acc_l2 * (L2_REG_F / (float)B_SZ);
    if (lane == 0) red[wave] = combined;
    __syncthreads();
    if (threadIdx.x == 0)
        partial[blockIdx.x] = red[0] + red[1] + red[2] + red[3];
}

__global__ __launch_bounds__(256) void finalize_kernel(const float* __restrict__ partial,
                                                       float* __restrict__ out) {
    __shared__ float red[4];
    const int wave = threadIdx.x >> 6;
    const int lane = threadIdx.x & 63;
    float v = 0.f;
    #pragma unroll
    for (int j = 0; j < NBLK / 256; ++j)
        v += partial[threadIdx.x + 256 * j];
    v = wave_reduce_sum(v);
    if (lane == 0) red[wave] = v;
    __syncthreads();
    if (threadIdx.x == 0)
        out[0] = red[0] + red[1] + red[2] + red[3];
}

extern "C" void kernel_launch(void* const* d_in, const int* in_sizes, int n_in,
                              void* d_out, int out_size, void* d_ws, size_t ws_size,
                              hipStream_t stream) {
    const float* embed = (const float*)d_in[0];
    const int*   anc   = (const int*)d_in[1];
    const int*   pos   = (const int*)d_in[2];
    const int*   neg   = (const int*)d_in[3];
    float* out     = (float*)d_out;
    float* partial = (float*)d_ws;            // NBLK floats, fully overwritten

    main_kernel<<<NBLK, 256, 0, stream>>>(embed, anc, pos, neg, partial);
    finalize_kernel<<<1, 256, 0, stream>>>(partial, out);
}

// Round 4
// 92.968 us; speedup vs baseline: 4.2543x; 1.2099x over previous
//
#include <hip/hip_runtime.h>
#include <hip/hip_bf16.h>
#include <math.h>

#define B_SZ 16384
#define D_DIM 128
#define A_SZ 8192
#define K_SZ 64
#define L2_REG_F 0.25f
#define CONV_BLK 512   // convert kernel blocks (x4 waves -> 8 rows/wave)
#define NBLK 2048      // main kernel blocks: 1 wave per anchor

__device__ __forceinline__ float wave_reduce_sum(float v) {
    #pragma unroll
    for (int off = 32; off > 0; off >>= 1)
        v += __shfl_xor(v, off, 64);
    return v;
}

__device__ __forceinline__ float wave_reduce_max(float v) {
    #pragma unroll
    for (int off = 32; off > 0; off >>= 1)
        v = fmaxf(v, __shfl_xor(v, off, 64));
    return v;
}

// unpack packed bf16 pair (low / high ushort of a uint) to float
__device__ __forceinline__ float blo(unsigned u) { return __uint_as_float(u << 16); }
__device__ __forceinline__ float bhi(unsigned u) { return __uint_as_float(u & 0xFFFF0000u); }

// Pre-pass: fp32 table -> bf16 table (4 MB, fits per-XCD L2) fused with
// the L2-norm sum (the only streaming read of the fp32 table).
__global__ __launch_bounds__(256) void convert_kernel(const float* __restrict__ embed,
                                                      unsigned* __restrict__ tab,
                                                      float* __restrict__ partial) {
    __shared__ float red[4];
    const int wave = threadIdx.x >> 6;
    const int lane = threadIdx.x & 63;
    const int gw   = blockIdx.x * 4 + wave;           // 0..2047
    float acc = 0.f;
    #pragma unroll
    for (int r = 0; r < B_SZ / (CONV_BLK * 4); ++r) { // 8 contiguous rows/wave
        const int row = gw * (B_SZ / (CONV_BLK * 4)) + r;
        const float2* rr = (const float2*)(embed + (size_t)row * D_DIM);
        float2 v = rr[lane];
        acc += sqrtf(wave_reduce_sum(v.x * v.x + v.y * v.y));  // exact fp32 norm
        __hip_bfloat16 bx = __float2bfloat16(v.x);             // RNE
        __hip_bfloat16 by = __float2bfloat16(v.y);
        tab[(size_t)row * 64 + lane] = ((unsigned)__bfloat16_as_ushort(by) << 16)
                                     | (unsigned)__bfloat16_as_ushort(bx);
    }
    if (lane == 0) red[wave] = acc * (L2_REG_F / (float)B_SZ); // pre-scaled
    __syncthreads();
    if (threadIdx.x == 0)
        partial[blockIdx.x] = red[0] + red[1] + red[2] + red[3];
}

// Main: one wave per anchor, lane k = negative k; all gathers from bf16 table.
__global__ __launch_bounds__(256) void npair_kernel(const unsigned* __restrict__ tab,
                                                    const int* __restrict__ anc_ind,
                                                    const int* __restrict__ pos_ind,
                                                    const int* __restrict__ neg_ind,
                                                    float* __restrict__ partial) {
    __shared__ __align__(16) float a_lds[4][D_DIM];
    __shared__ float red[4];
    const int wave = threadIdx.x >> 6;
    const int lane = threadIdx.x & 63;
    const int i    = blockIdx.x * 4 + wave;           // anchor id 0..8191

    const int ai = anc_ind[i];
    const int pi = pos_ind[i];
    const int ni = neg_ind[(size_t)i * K_SZ + lane];  // coalesced 256B

    unsigned ua = tab[(size_t)ai * 64 + lane];        // 2 bf16 elems per lane
    unsigned up = tab[(size_t)pi * 64 + lane];
    float ax = blo(ua), ay = bhi(ua);
    a_lds[wave][2 * lane]     = ax;
    a_lds[wave][2 * lane + 1] = ay;
    float ap = wave_reduce_sum(ax * blo(up) + ay * bhi(up));  // a.p broadcast

    // dot(a, n_k): 16x uint4 (8 bf16 each) from lane's gathered row; LDS a is
    // same-address broadcast across the wave (conflict-free).
    const uint4*  nr = (const uint4*)(tab + (size_t)ni * 64);
    const float4* al = (const float4*)a_lds[wave];
    float s0 = 0.f, s1 = 0.f;
    #pragma unroll
    for (int j = 0; j < 16; j += 4) {
        uint4 q0 = nr[j], q1 = nr[j + 1], q2 = nr[j + 2], q3 = nr[j + 3];
        float4 a0 = al[2 * j + 0], a1 = al[2 * j + 1];
        float4 a2 = al[2 * j + 2], a3 = al[2 * j + 3];
        float4 a4 = al[2 * j + 4], a5 = al[2 * j + 5];
        float4 a6 = al[2 * j + 6], a7 = al[2 * j + 7];
        s0 += a0.x * blo(q0.x) + a0.y * bhi(q0.x) + a0.z * blo(q0.y) + a0.w * bhi(q0.y);
        s1 += a1.x * blo(q0.z) + a1.y * bhi(q0.z) + a1.z * blo(q0.w) + a1.w * bhi(q0.w);
        s0 += a2.x * blo(q1.x) + a2.y * bhi(q1.x) + a2.z * blo(q1.y) + a2.w * bhi(q1.y);
        s1 += a3.x * blo(q1.z) + a3.y * bhi(q1.z) + a3.z * blo(q1.w) + a3.w * bhi(q1.w);
        s0 += a4.x * blo(q2.x) + a4.y * bhi(q2.x) + a4.z * blo(q2.y) + a4.w * bhi(q2.y);
        s1 += a5.x * blo(q2.z) + a5.y * bhi(q2.z) + a5.z * blo(q2.w) + a5.w * bhi(q2.w);
        s0 += a6.x * blo(q3.x) + a6.y * bhi(q3.x) + a6.z * blo(q3.y) + a6.w * bhi(q3.y);
        s1 += a7.x * blo(q3.z) + a7.y * bhi(q3.z) + a7.z * blo(q3.w) + a7.w * bhi(q3.w);
    }
    float inner = (s0 + s1) - ap;

    float m  = wave_reduce_max(inner);
    float se = wave_reduce_sum(__expf(inner - m));
    float lse = m + __logf(se);
    float per = (lse > 0.f) ? lse + log1pf(__expf(-lse)) : log1pf(__expf(lse));

    if (lane == 0) red[wave] = per * (1.0f / (float)A_SZ);    // pre-scaled
    __syncthreads();
    if (threadIdx.x == 0)
        partial[blockIdx.x] = red[0] + red[1] + red[2] + red[3];
}

// ---- fp32 fallback (used only if ws_size can't hold the bf16 table) ----
__global__ __launch_bounds__(256) void f32_kernel(const float* __restrict__ embed,
                                                  const int* __restrict__ anc_ind,
                                                  const int* __restrict__ pos_ind,
                                                  const int* __restrict__ neg_ind,
                                                  float* __restrict__ partial) {
    __shared__ __align__(16) float a_lds[4][D_DIM];
    __shared__ float red[4];
    const int wave = threadIdx.x >> 6;
    const int lane = threadIdx.x & 63;
    const int gw   = blockIdx.x * 4 + wave;

    float acc_l2 = 0.f;
    #pragma unroll
    for (int r = 0; r < 2; ++r) {
        const int row = gw * 2 + r;
        const float2* rr = (const float2*)(embed + (size_t)row * D_DIM);
        float2 v = rr[lane];
        acc_l2 += sqrtf(wave_reduce_sum(v.x * v.x + v.y * v.y));
    }
    const int i  = gw;
    const int ai = anc_ind[i];
    const int pi = pos_ind[i];
    const int ni = neg_ind[(size_t)i * K_SZ + lane];
    const float2* ar = (const float2*)(embed + (size_t)ai * D_DIM);
    const float2* pr = (const float2*)(embed + (size_t)pi * D_DIM);
    float2 a2 = ar[lane];
    float2 p2 = pr[lane];
    a_lds[wave][2 * lane]     = a2.x;
    a_lds[wave][2 * lane + 1] = a2.y;
    float ap = wave_reduce_sum(a2.x * p2.x + a2.y * p2.y);
    const float4* nr = (const float4*)(embed + (size_t)ni * D_DIM);
    const float4* al = (const float4*)a_lds[wave];
    float s0 = 0.f, s1 = 0.f, s2 = 0.f, s3 = 0.f;
    #pragma unroll
    for (int j = 0; j < D_DIM / 4; j += 4) {
        float4 n0 = nr[j], n1 = nr[j + 1], n2 = nr[j + 2], n3 = nr[j + 3];
        float4 a0 = al[j], a1 = al[j + 1], a2v = al[j + 2], a3 = al[j + 3];
        s0 += a0.x * n0.x + a0.y * n0.y + a0.z * n0.z + a0.w * n0.w;
        s1 += a1.x * n1.x + a1.y * n1.y + a1.z * n1.z + a1.w * n1.w;
        s2 += a2v.x * n2.x + a2v.y * n2.y + a2v.z * n2.z + a2v.w * n2.w;
        s3 += a3.x * n3.x + a3.y * n3.y + a3.z * n3.z + a3.w * n3.w;
    }
    float inner = (s0 + s1) + (s2 + s3) - ap;
    float m  = wave_reduce_max(inner);
    float se = wave_reduce_sum(__expf(inner - m));
    float lse = m + __logf(se);
    float per = (lse > 0.f) ? lse + log1pf(__expf(-lse)) : log1pf(__expf(lse));
    float combined = per * (1.0f / (float)A_SZ) + acc_l2 * (L2_REG_F / (float)B_SZ);
    if (lane == 0) red[wave] = combined;
    __syncthreads();
    if (threadIdx.x == 0)
        partial[blockIdx.x] = red[0] + red[1] + red[2] + red[3];
}

__global__ __launch_bounds__(256) void finalize_kernel(const float* __restrict__ partial,
                                                       int n, float* __restrict__ out) {
    __shared__ float red[4];
    const int wave = threadIdx.x >> 6;
    const int lane = threadIdx.x & 63;
    float v = 0.f;
    for (int j = threadIdx.x; j < n; j += 256) v += partial[j];
    v = wave_reduce_sum(v);
    if (lane == 0) red[wave] = v;
    __syncthreads();
    if (threadIdx.x == 0)
        out[0] = red[0] + red[1] + red[2] + red[3];
}

extern "C" void kernel_launch(void* const* d_in, const int* in_sizes, int n_in,
                              void* d_out, int out_size, void* d_ws, size_t ws_size,
                              hipStream_t stream) {
    const float* embed = (const float*)d_in[0];
    const int*   anc   = (const int*)d_in[1];
    const int*   pos   = (const int*)d_in[2];
    const int*   neg   = (const int*)d_in[3];
    float* out = (float*)d_out;

    const size_t tab_bytes = (size_t)B_SZ * (D_DIM / 2) * sizeof(unsigned); // 4 MB
    const size_t need = tab_bytes + (CONV_BLK + NBLK) * sizeof(float);

    if (ws_size >= need) {
        unsigned* tab     = (unsigned*)d_ws;
        float*    partial = (float*)((char*)d_ws + tab_bytes); // [conv | npair]
        convert_kernel<<<CONV_BLK, 256, 0, stream>>>(embed, tab, partial);
        npair_kernel<<<NBLK, 256, 0, stream>>>(tab, anc, pos, neg, partial + CONV_BLK);
        finalize_kernel<<<1, 256, 0, stream>>>(partial, CONV_BLK + NBLK, out);
    } else {
        float* partial = (float*)d_ws;
        f32_kernel<<<NBLK, 256, 0, stream>>>(embed, anc, pos, neg, partial);
        finalize_kernel<<<1, 256, 0, stream>>>(partial, NBLK, out);
    }
}

// Round 5
// 89.456 us; speedup vs baseline: 4.4213x; 1.0393x over previous
//
#include <hip/hip_runtime.h>
#include <hip/hip_bf16.h>
#include <math.h>

#define B_SZ 16384
#define D_DIM 128
#define A_SZ 8192
#define K_SZ 64
#define L2_REG_F 0.25f
#define CONV_BLK 512   // convert kernel blocks (x4 waves -> 8 rows/wave)
#define NBLK 2048      // main kernel blocks: 1 wave per anchor

__device__ __forceinline__ float wave_reduce_sum(float v) {
    #pragma unroll
    for (int off = 32; off > 0; off >>= 1)
        v += __shfl_xor(v, off, 64);
    return v;
}

__device__ __forceinline__ float wave_reduce_max(float v) {
    #pragma unroll
    for (int off = 32; off > 0; off >>= 1)
        v = fmaxf(v, __shfl_xor(v, off, 64));
    return v;
}

// unpack packed bf16 pair (low / high ushort of a uint) to float
__device__ __forceinline__ float blo(unsigned u) { return __uint_as_float(u << 16); }
__device__ __forceinline__ float bhi(unsigned u) { return __uint_as_float(u & 0xFFFF0000u); }

// Pre-pass: fp32 table -> bf16 table (4 MB, L2-resident) fused with the
// L2-norm sum (the only streaming read of the fp32 table).
__global__ __launch_bounds__(256) void convert_kernel(const float* __restrict__ embed,
                                                      unsigned* __restrict__ tab,
                                                      float* __restrict__ partial) {
    __shared__ float red[4];
    const int wave = threadIdx.x >> 6;
    const int lane = threadIdx.x & 63;
    const int gw   = blockIdx.x * 4 + wave;           // 0..2047
    float acc = 0.f;
    #pragma unroll
    for (int r = 0; r < B_SZ / (CONV_BLK * 4); ++r) { // 8 contiguous rows/wave
        const int row = gw * (B_SZ / (CONV_BLK * 4)) + r;
        const float2* rr = (const float2*)(embed + (size_t)row * D_DIM);
        float2 v = rr[lane];
        acc += sqrtf(wave_reduce_sum(v.x * v.x + v.y * v.y));  // exact fp32 norm
        __hip_bfloat16 bx = __float2bfloat16(v.x);             // RNE
        __hip_bfloat16 by = __float2bfloat16(v.y);
        tab[(size_t)row * 64 + lane] = ((unsigned)__bfloat16_as_ushort(by) << 16)
                                     | (unsigned)__bfloat16_as_ushort(bx);
    }
    if (lane == 0) red[wave] = acc * (L2_REG_F / (float)B_SZ); // pre-scaled
    __syncthreads();
    if (threadIdx.x == 0)
        partial[blockIdx.x] = red[0] + red[1] + red[2] + red[3];
}

// Main: one wave per anchor. Gather layout: 4 lanes cooperate per negative
// row (16 rows in flight per pass, 4 passes) so each global load instruction
// touches ~16 cache lines (contiguous 64B per row) instead of 64 random ones.
__global__ __launch_bounds__(256) void npair_kernel(const unsigned* __restrict__ tab,
                                                    const int* __restrict__ anc_ind,
                                                    const int* __restrict__ pos_ind,
                                                    const int* __restrict__ neg_ind,
                                                    float* __restrict__ partial) {
    __shared__ __align__(16) float a_lds[4][D_DIM];
    __shared__ float red[4];
    const int wave = threadIdx.x >> 6;
    const int lane = threadIdx.x & 63;
    const int i    = blockIdx.x * 4 + wave;           // anchor id 0..8191

    const int ai = anc_ind[i];
    const int pi = pos_ind[i];
    const int nid_all = neg_ind[(size_t)i * K_SZ + lane];  // coalesced 256B

    unsigned ua = tab[(size_t)ai * 64 + lane];        // 2 bf16 elems per lane
    unsigned up = tab[(size_t)pi * 64 + lane];
    float ax = blo(ua), ay = bhi(ua);
    a_lds[wave][2 * lane]     = ax;
    a_lds[wave][2 * lane + 1] = ay;
    float ap = wave_reduce_sum(ax * blo(up) + ay * bhi(up));  // a.p broadcast

    const float4* al = (const float4*)a_lds[wave];
    const int r = lane & 15;   // row within pass
    const int c = lane >> 4;   // 16B-chunk group 0..3

    float inner = 0.f;
    #pragma unroll
    for (int p = 0; p < 4; ++p) {                     // 16 negatives per pass
        const int nidx = __shfl(nid_all, p * 16 + r, 64);
        const uint4* nb = (const uint4*)(tab + (size_t)nidx * 64);
        float s = 0.f;
        #pragma unroll
        for (int j = 0; j < 4; ++j) {
            const int u = j * 4 + c;                  // uint4 index in the row
            uint4 q = nb[u];                          // 4 lanes cover contig 64B
            float4 a0 = al[2 * u], a1 = al[2 * u + 1]; // LDS broadcast x16 lanes
            s += a0.x * blo(q.x) + a0.y * bhi(q.x) + a0.z * blo(q.y) + a0.w * bhi(q.y);
            s += a1.x * blo(q.z) + a1.y * bhi(q.z) + a1.z * blo(q.w) + a1.w * bhi(q.w);
        }
        // reduce the 4 chunk-lanes (stride 16) -> full dot for row r
        s += __shfl_xor(s, 16, 64);
        s += __shfl_xor(s, 32, 64);
        if (c == p) inner = s;   // lane l keeps negative (l>>4)*16 + (l&15)
    }
    inner -= ap;                 // permutation of the 64 inners: LSE-invariant

    float m  = wave_reduce_max(inner);
    float se = wave_reduce_sum(__expf(inner - m));
    float lse = m + __logf(se);
    float per = (lse > 0.f) ? lse + log1pf(__expf(-lse)) : log1pf(__expf(lse));

    if (lane == 0) red[wave] = per * (1.0f / (float)A_SZ);    // pre-scaled
    __syncthreads();
    if (threadIdx.x == 0)
        partial[blockIdx.x] = red[0] + red[1] + red[2] + red[3];
}

// ---- fp32 fallback (used only if ws_size can't hold the bf16 table) ----
__global__ __launch_bounds__(256) void f32_kernel(const float* __restrict__ embed,
                                                  const int* __restrict__ anc_ind,
                                                  const int* __restrict__ pos_ind,
                                                  const int* __restrict__ neg_ind,
                                                  float* __restrict__ partial) {
    __shared__ __align__(16) float a_lds[4][D_DIM];
    __shared__ float red[4];
    const int wave = threadIdx.x >> 6;
    const int lane = threadIdx.x & 63;
    const int gw   = blockIdx.x * 4 + wave;

    float acc_l2 = 0.f;
    #pragma unroll
    for (int r = 0; r < 2; ++r) {
        const int row = gw * 2 + r;
        const float2* rr = (const float2*)(embed + (size_t)row * D_DIM);
        float2 v = rr[lane];
        acc_l2 += sqrtf(wave_reduce_sum(v.x * v.x + v.y * v.y));
    }
    const int i  = gw;
    const int ai = anc_ind[i];
    const int pi = pos_ind[i];
    const int ni = neg_ind[(size_t)i * K_SZ + lane];
    const float2* ar = (const float2*)(embed + (size_t)ai * D_DIM);
    const float2* pr = (const float2*)(embed + (size_t)pi * D_DIM);
    float2 a2 = ar[lane];
    float2 p2 = pr[lane];
    a_lds[wave][2 * lane]     = a2.x;
    a_lds[wave][2 * lane + 1] = a2.y;
    float ap = wave_reduce_sum(a2.x * p2.x + a2.y * p2.y);
    const float4* nr = (const float4*)(embed + (size_t)ni * D_DIM);
    const float4* al = (const float4*)a_lds[wave];
    float s0 = 0.f, s1 = 0.f, s2 = 0.f, s3 = 0.f;
    #pragma unroll
    for (int j = 0; j < D_DIM / 4; j += 4) {
        float4 n0 = nr[j], n1 = nr[j + 1], n2 = nr[j + 2], n3 = nr[j + 3];
        float4 a0 = al[j], a1 = al[j + 1], a2v = al[j + 2], a3 = al[j + 3];
        s0 += a0.x * n0.x + a0.y * n0.y + a0.z * n0.z + a0.w * n0.w;
        s1 += a1.x * n1.x + a1.y * n1.y + a1.z * n1.z + a1.w * n1.w;
        s2 += a2v.x * n2.x + a2v.y * n2.y + a2v.z * n2.z + a2v.w * n2.w;
        s3 += a3.x * n3.x + a3.y * n3.y + a3.z * n3.z + a3.w * n3.w;
    }
    float inner = (s0 + s1) + (s2 + s3) - ap;
    float m  = wave_reduce_max(inner);
    float se = wave_reduce_sum(__expf(inner - m));
    float lse = m + __logf(se);
    float per = (lse > 0.f) ? lse + log1pf(__expf(-lse)) : log1pf(__expf(lse));
    float combined = per * (1.0f / (float)A_SZ) + acc_l2 * (L2_REG_F / (float)B_SZ);
    if (lane == 0) red[wave] = combined;
    __syncthreads();
    if (threadIdx.x == 0)
        partial[blockIdx.x] = red[0] + red[1] + red[2] + red[3];
}

__global__ __launch_bounds__(256) void finalize_kernel(const float* __restrict__ partial,
                                                       int n, float* __restrict__ out) {
    __shared__ float red[4];
    const int wave = threadIdx.x >> 6;
    const int lane = threadIdx.x & 63;
    float v = 0.f;
    for (int j = threadIdx.x; j < n; j += 256) v += partial[j];
    v = wave_reduce_sum(v);
    if (lane == 0) red[wave] = v;
    __syncthreads();
    if (threadIdx.x == 0)
        out[0] = red[0] + red[1] + red[2] + red[3];
}

extern "C" void kernel_launch(void* const* d_in, const int* in_sizes, int n_in,
                              void* d_out, int out_size, void* d_ws, size_t ws_size,
                              hipStream_t stream) {
    const float* embed = (const float*)d_in[0];
    const int*   anc   = (const int*)d_in[1];
    const int*   pos   = (const int*)d_in[2];
    const int*   neg   = (const int*)d_in[3];
    float* out = (float*)d_out;

    const size_t tab_bytes = (size_t)B_SZ * (D_DIM / 2) * sizeof(unsigned); // 4 MB
    const size_t need = tab_bytes + (CONV_BLK + NBLK) * sizeof(float);

    if (ws_size >= need) {
        unsigned* tab     = (unsigned*)d_ws;
        float*    partial = (float*)((char*)d_ws + tab_bytes); // [conv | npair]
        convert_kernel<<<CONV_BLK, 256, 0, stream>>>(embed, tab, partial);
        npair_kernel<<<NBLK, 256, 0, stream>>>(tab, anc, pos, neg, partial + CONV_BLK);
        finalize_kernel<<<1, 256, 0, stream>>>(partial, CONV_BLK + NBLK, out);
    } else {
        float* partial = (float*)d_ws;
        f32_kernel<<<NBLK, 256, 0, stream>>>(embed, anc, pos, neg, partial);
        finalize_kernel<<<1, 256, 0, stream>>>(partial, NBLK, out);
    }
}

// Round 6
// 80.504 us; speedup vs baseline: 4.9129x; 1.1112x over previous
//
#include <hip/hip_runtime.h>
#include <hip/hip_bf16.h>
#include <math.h>

#define B_SZ 16384
#define D_DIM 128
#define A_SZ 8192
#define K_SZ 64
#define L2_REG_F 0.25f
#define CONV_BLK 512   // convert kernel blocks (x4 waves -> 8 rows/wave)
#define NBLK 2048      // main kernel blocks: 1 wave per anchor

typedef float vfloat2 __attribute__((ext_vector_type(2)));

__device__ __forceinline__ float wave_reduce_sum(float v) {
    #pragma unroll
    for (int off = 32; off > 0; off >>= 1)
        v += __shfl_xor(v, off, 64);
    return v;
}

__device__ __forceinline__ float wave_reduce_max(float v) {
    #pragma unroll
    for (int off = 32; off > 0; off >>= 1)
        v = fmaxf(v, __shfl_xor(v, off, 64));
    return v;
}

// Pre-pass: fp32 table -> fp8 e4m3 table (2 MB, L2-resident) fused with the
// exact-fp32 L2-norm sum (the only full streaming read of the fp32 table).
__global__ __launch_bounds__(256) void convert_kernel(const float* __restrict__ embed,
                                                      unsigned short* __restrict__ tab,
                                                      float* __restrict__ partial) {
    __shared__ float red[4];
    const int wave = threadIdx.x >> 6;
    const int lane = threadIdx.x & 63;
    const int gw   = blockIdx.x * 4 + wave;           // 0..2047
    float acc = 0.f;
    #pragma unroll
    for (int r = 0; r < B_SZ / (CONV_BLK * 4); ++r) { // 8 contiguous rows/wave
        const int row = gw * (B_SZ / (CONV_BLK * 4)) + r;
        const float2* rr = (const float2*)(embed + (size_t)row * D_DIM);
        float2 v = rr[lane];                          // elems 2*lane, 2*lane+1
        acc += sqrtf(wave_reduce_sum(v.x * v.x + v.y * v.y));  // exact fp32 norm
        // HW RNE fp32->fp8 e4m3 (OCP on gfx950), 2 elems packed in low ushort
        unsigned pk = (unsigned)__builtin_amdgcn_cvt_pk_fp8_f32(v.x, v.y, 0, false);
        tab[(size_t)row * 64 + lane] = (unsigned short)pk;
    }
    if (lane == 0) red[wave] = acc * (L2_REG_F / (float)B_SZ); // pre-scaled
    __syncthreads();
    if (threadIdx.x == 0)
        partial[blockIdx.x] = red[0] + red[1] + red[2] + red[3];
}

// Main: one wave per anchor. Negatives from the fp8 table: 8 lanes cooperate
// per row (row = 128 B = 2 cache lines; 16 lines per load instruction), and
// ALL 8 gather loads are issued up-front (no inter-load dependencies) for
// full memory-level parallelism. a/p stay exact fp32.
__global__ __launch_bounds__(256) void npair_kernel(const float* __restrict__ embed,
                                                    const unsigned short* __restrict__ tab,
                                                    const int* __restrict__ anc_ind,
                                                    const int* __restrict__ pos_ind,
                                                    const int* __restrict__ neg_ind,
                                                    float* __restrict__ partial) {
    __shared__ __align__(16) float a_lds[4][D_DIM];
    __shared__ float red[4];
    const int wave = threadIdx.x >> 6;
    const int lane = threadIdx.x & 63;
    const int i    = blockIdx.x * 4 + wave;           // anchor id 0..8191

    const int ai = anc_ind[i];
    const int pi = pos_ind[i];
    const int nid_all = neg_ind[(size_t)i * K_SZ + lane];  // coalesced 256B

    const float2* ar = (const float2*)(embed + (size_t)ai * D_DIM);
    const float2* pr = (const float2*)(embed + (size_t)pi * D_DIM);
    float2 a2 = ar[lane];
    float2 p2 = pr[lane];
    a_lds[wave][2 * lane]     = a2.x;
    a_lds[wave][2 * lane + 1] = a2.y;
    float ap = wave_reduce_sum(a2.x * p2.x + a2.y * p2.y);  // exact a.p, broadcast

    const int g = lane >> 3;   // row-in-pass 0..7 (8 consecutive lanes per row)
    const int c = lane & 7;    // 16B chunk 0..7 within the 128B row

    // pre-shuffle all 8 row indices (pass p covers negatives p*8 + g)
    int nidx[8];
    #pragma unroll
    for (int p = 0; p < 8; ++p)
        nidx[p] = __shfl(nid_all, p * 8 + g, 64);

    // issue all 8 independent gather loads
    uint4 q[8];
    #pragma unroll
    for (int p = 0; p < 8; ++p)
        q[p] = ((const uint4*)(tab + (size_t)nidx[p] * 64))[c];

    // this lane's a-subvector (elems c*16 .. c*16+15), reused across all passes
    const float4* al = (const float4*)a_lds[wave];
    float4 A0 = al[c * 4 + 0], A1 = al[c * 4 + 1];
    float4 A2 = al[c * 4 + 2], A3 = al[c * 4 + 3];

    float inner = 0.f;
    #pragma unroll
    for (int p = 0; p < 8; ++p) {
        uint4 qq = q[p];
        vfloat2 f0 = __builtin_amdgcn_cvt_pk_f32_fp8(qq.x, false);
        vfloat2 f1 = __builtin_amdgcn_cvt_pk_f32_fp8(qq.x, true);
        vfloat2 f2 = __builtin_amdgcn_cvt_pk_f32_fp8(qq.y, false);
        vfloat2 f3 = __builtin_amdgcn_cvt_pk_f32_fp8(qq.y, true);
        vfloat2 f4 = __builtin_amdgcn_cvt_pk_f32_fp8(qq.z, false);
        vfloat2 f5 = __builtin_amdgcn_cvt_pk_f32_fp8(qq.z, true);
        vfloat2 f6 = __builtin_amdgcn_cvt_pk_f32_fp8(qq.w, false);
        vfloat2 f7 = __builtin_amdgcn_cvt_pk_f32_fp8(qq.w, true);
        float s = A0.x * f0.x + A0.y * f0.y + A0.z * f1.x + A0.w * f1.y
                + A1.x * f2.x + A1.y * f2.y + A1.z * f3.x + A1.w * f3.y
                + A2.x * f4.x + A2.y * f4.y + A2.z * f5.x + A2.w * f5.y
                + A3.x * f6.x + A3.y * f6.y + A3.z * f7.x + A3.w * f7.y;
        // reduce the 8 chunk-lanes (xor 1,2,4) -> full dot of row p*8+g
        s += __shfl_xor(s, 1, 64);
        s += __shfl_xor(s, 2, 64);
        s += __shfl_xor(s, 4, 64);
        if (c == p) inner = s;   // lane l keeps negative (l&7)*8 + (l>>3)
    }
    inner -= ap;                 // permutation of the 64 inners: LSE-invariant

    float m  = wave_reduce_max(inner);
    float se = wave_reduce_sum(__expf(inner - m));
    float lse = m + __logf(se);
    float per = (lse > 0.f) ? lse + log1pf(__expf(-lse)) : log1pf(__expf(lse));

    if (lane == 0) red[wave] = per * (1.0f / (float)A_SZ);    // pre-scaled
    __syncthreads();
    if (threadIdx.x == 0)
        partial[blockIdx.x] = red[0] + red[1] + red[2] + red[3];
}

// ---- fp32 fallback (used only if ws_size can't hold the fp8 table) ----
__global__ __launch_bounds__(256) void f32_kernel(const float* __restrict__ embed,
                                                  const int* __restrict__ anc_ind,
                                                  const int* __restrict__ pos_ind,
                                                  const int* __restrict__ neg_ind,
                                                  float* __restrict__ partial) {
    __shared__ __align__(16) float a_lds[4][D_DIM];
    __shared__ float red[4];
    const int wave = threadIdx.x >> 6;
    const int lane = threadIdx.x & 63;
    const int gw   = blockIdx.x * 4 + wave;

    float acc_l2 = 0.f;
    #pragma unroll
    for (int r = 0; r < 2; ++r) {
        const int row = gw * 2 + r;
        const float2* rr = (const float2*)(embed + (size_t)row * D_DIM);
        float2 v = rr[lane];
        acc_l2 += sqrtf(wave_reduce_sum(v.x * v.x + v.y * v.y));
    }
    const int i  = gw;
    const int ai = anc_ind[i];
    const int pi = pos_ind[i];
    const int ni = neg_ind[(size_t)i * K_SZ + lane];
    const float2* ar = (const float2*)(embed + (size_t)ai * D_DIM);
    const float2* pr = (const float2*)(embed + (size_t)pi * D_DIM);
    float2 a2 = ar[lane];
    float2 p2 = pr[lane];
    a_lds[wave][2 * lane]     = a2.x;
    a_lds[wave][2 * lane + 1] = a2.y;
    float ap = wave_reduce_sum(a2.x * p2.x + a2.y * p2.y);
    const float4* nr = (const float4*)(embed + (size_t)ni * D_DIM);
    const float4* al = (const float4*)a_lds[wave];
    float s0 = 0.f, s1 = 0.f, s2 = 0.f, s3 = 0.f;
    #pragma unroll
    for (int j = 0; j < D_DIM / 4; j += 4) {
        float4 n0 = nr[j], n1 = nr[j + 1], n2 = nr[j + 2], n3 = nr[j + 3];
        float4 a0 = al[j], a1 = al[j + 1], a2v = al[j + 2], a3 = al[j + 3];
        s0 += a0.x * n0.x + a0.y * n0.y + a0.z * n0.z + a0.w * n0.w;
        s1 += a1.x * n1.x + a1.y * n1.y + a1.z * n1.z + a1.w * n1.w;
        s2 += a2v.x * n2.x + a2v.y * n2.y + a2v.z * n2.z + a2v.w * n2.w;
        s3 += a3.x * n3.x + a3.y * n3.y + a3.z * n3.z + a3.w * n3.w;
    }
    float inner = (s0 + s1) + (s2 + s3) - ap;
    float m  = wave_reduce_max(inner);
    float se = wave_reduce_sum(__expf(inner - m));
    float lse = m + __logf(se);
    float per = (lse > 0.f) ? lse + log1pf(__expf(-lse)) : log1pf(__expf(lse));
    float combined = per * (1.0f / (float)A_SZ) + acc_l2 * (L2_REG_F / (float)B_SZ);
    if (lane == 0) red[wave] = combined;
    __syncthreads();
    if (threadIdx.x == 0)
        partial[blockIdx.x] = red[0] + red[1] + red[2] + red[3];
}

__global__ __launch_bounds__(256) void finalize_kernel(const float* __restrict__ partial,
                                                       int n, float* __restrict__ out) {
    __shared__ float red[4];
    const int wave = threadIdx.x >> 6;
    const int lane = threadIdx.x & 63;
    float v = 0.f;
    for (int j = threadIdx.x; j < n; j += 256) v += partial[j];
    v = wave_reduce_sum(v);
    if (lane == 0) red[wave] = v;
    __syncthreads();
    if (threadIdx.x == 0)
        out[0] = red[0] + red[1] + red[2] + red[3];
}

extern "C" void kernel_launch(void* const* d_in, const int* in_sizes, int n_in,
                              void* d_out, int out_size, void* d_ws, size_t ws_size,
                              hipStream_t stream) {
    const float* embed = (const float*)d_in[0];
    const int*   anc   = (const int*)d_in[1];
    const int*   pos   = (const int*)d_in[2];
    const int*   neg   = (const int*)d_in[3];
    float* out = (float*)d_out;

    const size_t tab_bytes = (size_t)B_SZ * D_DIM; // 2 MB fp8
    const size_t need = tab_bytes + (CONV_BLK + NBLK) * sizeof(float);

    if (ws_size >= need) {
        unsigned short* tab = (unsigned short*)d_ws;
        float* partial = (float*)((char*)d_ws + tab_bytes); // [conv | npair]
        convert_kernel<<<CONV_BLK, 256, 0, stream>>>(embed, tab, partial);
        npair_kernel<<<NBLK, 256, 0, stream>>>(embed, tab, anc, pos, neg, partial + CONV_BLK);
        finalize_kernel<<<1, 256, 0, stream>>>(partial, CONV_BLK + NBLK, out);
    } else {
        float* partial = (float*)d_ws;
        f32_kernel<<<NBLK, 256, 0, stream>>>(embed, anc, pos, neg, partial);
        finalize_kernel<<<1, 256, 0, stream>>>(partial, NBLK, out);
    }
}